// Round 7
// baseline (111.000 us; speedup 1.0000x reference)
//
#include <hip/hip_runtime.h>
#include <hip/hip_bf16.h>

typedef __attribute__((ext_vector_type(8)))  __bf16 bf16x8;
typedef __attribute__((ext_vector_type(4)))  __bf16 bf16x4;
typedef __attribute__((ext_vector_type(2)))  __bf16 bf16x2;
typedef __attribute__((ext_vector_type(4)))  float  f32x4;
typedef __attribute__((ext_vector_type(16))) float  f32x16;

#define MFMA16(a,b,c) __builtin_amdgcn_mfma_f32_16x16x32_bf16((a),(b),(c),0,0,0)
#define MFMA32(a,b,c) __builtin_amdgcn_mfma_f32_32x32x16_bf16((a),(b),(c),0,0,0)

__device__ inline void gload_lds16(const __bf16* g, __bf16* l) {
  __builtin_amdgcn_global_load_lds(
      (const __attribute__((address_space(1))) void*)g,
      (__attribute__((address_space(3))) void*)l, 16, 0, 0);
}

// ---------------------------------------------------------------------------
// Projection GEMM, f32 inputs with FUSED bf16 conversion in reg-staging.
// dst = relu(X @ W^T + bias) * oscale. One barrier per k-step:
//   issue f32 loads(t+1) -> sync -> MFMA(cur) -> cvt+ds_write(cur^1).
// z=0: Q scaled by log2e/sqrt(128), masked rows zeroed -> [bh][s][d].
// z=1: K [bh][s][d]. z=2: V^T [bh][d][s].
// ---------------------------------------------------------------------------
__global__ __launch_bounds__(256, 2) void gemm_kernel(
    const float* __restrict__ Xq, const float* __restrict__ Xk,
    const float* __restrict__ Xv, const float* __restrict__ Wq,
    const float* __restrict__ Wk, const float* __restrict__ Wv,
    const float* __restrict__ bq, const float* __restrict__ bk,
    const float* __restrict__ bv, const int* __restrict__ mask,
    __bf16* __restrict__ dq, __bf16* __restrict__ dk, __bf16* __restrict__ dv)
{
  const int which = blockIdx.z;
  const float* X    = which == 0 ? Xq : which == 1 ? Xk : Xv;
  const float* W    = which == 0 ? Wq : which == 1 ? Wk : Wv;
  const float* bias = which == 0 ? bq : which == 1 ? bk : bv;
  __bf16* dst       = which == 0 ? dq : which == 1 ? dk : dv;
  const float oscale = which == 0 ? 0.12751744710339033f : 1.0f; // log2e/sqrt(128)
  const int mode = (which == 2);

  // [128][64] bf16, 16B slot s stored at s^(row&7)
  __shared__ __align__(16) __bf16 Al[2][128 * 64];
  __shared__ __align__(16) __bf16 Bl[2][128 * 64];

  const int tid  = threadIdx.x;
  const int lane = tid & 63;
  const int w    = tid >> 6;
  const int wr = w >> 1, wc = w & 1;
  const int mbase = blockIdx.x * 128;
  const int nbase = blockIdx.y * 128;
  const int arow = lane & 15;
  const int hi   = lane >> 4;

  f32x4 acc[4][4] = {};
  float4 ar[8], br[8];

  auto issue = [&](int k0) {
#pragma unroll
    for (int i = 0; i < 8; ++i) {
      int idx = tid + i * 256;
      int r = idx >> 4, c = (idx & 15) * 4;
      ar[i] = *(const float4*)&X[(size_t)(mbase + r) * 512 + k0 + c];
      br[i] = *(const float4*)&W[(size_t)(nbase + r) * 512 + k0 + c];
    }
  };
  auto commit = [&](int buf) {
#pragma unroll
    for (int i = 0; i < 8; ++i) {
      int idx = tid + i * 256;
      int r = idx >> 4, c4 = idx & 15;
      int slot = c4 >> 1, half = c4 & 1;
      int addr = r * 64 + (slot ^ (r & 7)) * 8 + half * 4;
      bf16x4 av, bv2;
      av[0] = (__bf16)ar[i].x; av[1] = (__bf16)ar[i].y;
      av[2] = (__bf16)ar[i].z; av[3] = (__bf16)ar[i].w;
      bv2[0] = (__bf16)br[i].x; bv2[1] = (__bf16)br[i].y;
      bv2[2] = (__bf16)br[i].z; bv2[3] = (__bf16)br[i].w;
      *(bf16x4*)&Al[buf][addr] = av;
      *(bf16x4*)&Bl[buf][addr] = bv2;
    }
  };

  issue(0);
  commit(0);

  for (int t = 0; t < 8; ++t) {
    const int cur = t & 1;
    if (t < 7) issue((t + 1) * 64);
    __syncthreads();

    __builtin_amdgcn_s_setprio(1);
#pragma unroll
    for (int kk = 0; kk < 2; ++kk) {
      bf16x8 af[4], bfr[4];
#pragma unroll
      for (int m = 0; m < 4; ++m) {
        int row = wr * 64 + m * 16 + arow;
        int sl  = ((kk * 4 + hi) ^ (row & 7)) * 8;
        af[m] = *(bf16x8*)&Al[cur][row * 64 + sl];
      }
#pragma unroll
      for (int n = 0; n < 4; ++n) {
        int row = wc * 64 + n * 16 + arow;
        int sl  = ((kk * 4 + hi) ^ (row & 7)) * 8;
        bfr[n] = *(bf16x8*)&Bl[cur][row * 64 + sl];
      }
#pragma unroll
      for (int m = 0; m < 4; ++m)
#pragma unroll
        for (int n = 0; n < 4; ++n)
          acc[m][n] = MFMA16(af[m], bfr[n], acc[m][n]);
    }
    __builtin_amdgcn_s_setprio(0);

    if (t < 7) commit(cur ^ 1);
  }

  // Epilogue: bias + relu + oscale (+ Q row-mask zeroing), bf16 store.
#pragma unroll
  for (int n = 0; n < 4; ++n) {
    int col = nbase + wc * 64 + n * 16 + arow;
    float bsv = bias[col];
    int h = col >> 7, d = col & 127;
#pragma unroll
    for (int m = 0; m < 4; ++m) {
      int row0 = mbase + wr * 64 + m * 16 + hi * 4;
#pragma unroll
      for (int r = 0; r < 4; ++r) {
        float v = acc[m][n][r] + bsv;
        v = (v > 0.0f ? v : 0.0f) * oscale;
        int mm = row0 + r;
        int b = mm >> 11, s = mm & 2047;
        if (which == 0 && mask[b * 2048 + s] != 0) v = 0.0f;
        if (mode == 0)
          dst[((size_t)(b * 4 + h) * 2048 + s) * 128 + d] = (__bf16)v;
        else
          dst[((size_t)(b * 4 + h) * 128 + d) * 2048 + s] = (__bf16)v;
      }
    }
  }
}

// ---------------------------------------------------------------------------
// Flash attention, fixed-reference softmax (scores >= 0, bounded; masked rows
// arrive with Q==0 -> P==1 -> mean(V)). K LDS-staged (swizzled, dbuf,
// counted vmcnt); V read DIRECT from global into regs (L1/L2-resident tile).
// 32x32x16 swapped operands, KV-split-2, permlane32 P-exchange, l-only merge.
// ---------------------------------------------------------------------------
__global__ __launch_bounds__(256, 2) void attn_kernel(
    const __bf16* __restrict__ qh, const __bf16* __restrict__ kh,
    const __bf16* __restrict__ vt, const float* __restrict__ queries,
    float* __restrict__ out)
{
  __shared__ __align__(16) __bf16 Kl[2][64 * 128];  // [kv][d], slot ^ (row&7)
  __shared__ float Mbuf[64 + 128 * 68];             // merge: Ll + Ob

  const int tid  = threadIdx.x;
  const int lane = tid & 63;
  const int w    = tid >> 6;
  const int qw   = w & 1;
  const int kw   = w >> 1;
  const int r5   = lane & 31;
  const int hi32 = lane >> 5;

  const int blk = blockIdx.x;
  const int xcd = blk & 7;
  const int idx = blk >> 3;
  const int bh  = xcd * 2 + (idx & 1);
  const int qt  = idx >> 1;
  const int b = bh >> 2, h = bh & 3;
  const int qbase = qt * 64 + qw * 32;

  const __bf16* qptr = qh + (size_t)bh * 2048 * 128;
  const __bf16* kptr = kh + (size_t)bh * 2048 * 128;
  const __bf16* vptr = vt + (size_t)bh * 128 * 2048;

  bf16x8 qf[8];
#pragma unroll
  for (int ds = 0; ds < 8; ++ds)
    qf[ds] = *(const bf16x8*)&qptr[(size_t)(qbase + r5) * 128 + ds * 16 + hi32 * 8];

  float l_st = 0.f;
  f32x16 oacc[4] = {};

  auto stageK = [&](int buf, int kv0) {
#pragma unroll
    for (int i = 0; i < 4; ++i) {
      int ob = i * 4096 + w * 1024;
      int o  = ob + lane * 16;
      int r  = o >> 8;
      int s  = ((o >> 4) & 15) ^ (r & 7);
      gload_lds16(kptr + (size_t)(kv0 + r) * 128 + s * 8, &Kl[buf][ob >> 1]);
    }
  };

  stageK(0, 0);

  for (int t = 0; t < 32; ++t) {
    const int cur = t & 1;
    if (t < 31) {
      stageK(cur ^ 1, (t + 1) * 64);
      asm volatile("s_waitcnt vmcnt(4)" ::: "memory");  // K(t) resident
    } else {
      asm volatile("s_waitcnt vmcnt(0)" ::: "memory");
    }

    // V fragments for tile t: direct global->reg (L1/L2 hot), used after
    // QK^T + softmax (~1000+ cy of cover).
    bf16x8 vf[4][2];
#pragma unroll
    for (int dblk = 0; dblk < 4; ++dblk)
#pragma unroll
      for (int s = 0; s < 2; ++s) {
        int row  = dblk * 32 + r5;
        int slot = kw * 4 + s * 2 + hi32;
        vf[dblk][s] =
            *(const bf16x8*)&vptr[(size_t)row * 2048 + t * 64 + slot * 8];
      }

    __builtin_amdgcn_s_barrier();

    // QK^T swapped on this wave's kv-half: S[kv][q=lane&31] (log2 domain).
    f32x16 sacc = {};
    __builtin_amdgcn_s_setprio(1);
#pragma unroll
    for (int ds = 0; ds < 8; ++ds) {
      int row = kw * 32 + r5;
      int sl  = ((ds * 2 + hi32) ^ (row & 7)) * 8;
      bf16x8 kf = *(bf16x8*)&Kl[cur][row * 128 + sl];
      sacc = MFMA32(kf, qf[ds], sacc);
    }
    __builtin_amdgcn_s_setprio(0);

    // Fixed-reference softmax: P = exp2(s). Tree-sum to cut dep chain.
    float ps[16];
#pragma unroll
    for (int r = 0; r < 16; ++r) {
      ps[r] = __builtin_amdgcn_exp2f(sacc[r]);
      sacc[r] = ps[r];
    }
#pragma unroll
    for (int st = 1; st < 16; st <<= 1)
#pragma unroll
      for (int r = 0; r < 16; r += 2 * st)
        ps[r] += ps[r + st];
    l_st += ps[0];

    // P -> B-frags in-register: bf16 pack pairs + permlane32_swap.
    unsigned pk[8];
#pragma unroll
    for (int g = 0; g < 8; ++g) {
      bf16x2 tp;
      tp[0] = (__bf16)sacc[2 * g];
      tp[1] = (__bf16)sacc[2 * g + 1];
      pk[g] = __builtin_bit_cast(unsigned, tp);
    }
    bf16x8 pf[2];
#pragma unroll
    for (int s = 0; s < 2; ++s) {
      unsigned a0 = pk[4 * s + 0], a1 = pk[4 * s + 1];
      unsigned b0 = pk[4 * s + 2], b1 = pk[4 * s + 3];
      asm("v_permlane32_swap_b32 %0, %1" : "+v"(a0), "+v"(b0));
      asm("v_permlane32_swap_b32 %0, %1" : "+v"(a1), "+v"(b1));
      union { unsigned u[4]; bf16x8 v; } pu;
      pu.u[0] = a0; pu.u[1] = a1; pu.u[2] = b0; pu.u[3] = b1;
      pf[s] = pu.v;
    }

    __builtin_amdgcn_s_setprio(1);
#pragma unroll
    for (int dblk = 0; dblk < 4; ++dblk)
#pragma unroll
      for (int s = 0; s < 2; ++s)
        oacc[dblk] = MFMA32(vf[dblk][s], pf[s], oacc[dblk]);
    __builtin_amdgcn_s_setprio(0);

    __builtin_amdgcn_s_barrier();
  }

  // ---- merge kv-halves (l and O are plain sums), then epilogue ----
  float l_tot = l_st + __shfl_xor(l_st, 32);

  __syncthreads();
  float* Ll = Mbuf;                  // [2 qw][32 q]
  float* Ob = Mbuf + 64;             // kw=1 oacc, stride 68 f32/lane

  if (kw == 1) {
    if (hi32 == 0) Ll[qw * 32 + r5] = l_tot;
    float* dst = Ob + (size_t)(qw * 64 + lane) * 68;
#pragma unroll
    for (int dblk = 0; dblk < 4; ++dblk)
      *(f32x16*)(dst + dblk * 16) = oacc[dblk];
  }
  __syncthreads();

  if (kw == 0) {
    float l1 = Ll[qw * 32 + r5];
    float inv = 1.0f / (l_tot + l1);
    const float* src = Ob + (size_t)(qw * 64 + lane) * 68;

    const int qhi = qt >> 3;
    const int col = (qt & 7) * 64 + qw * 32 + r5;
#pragma unroll
    for (int dblk = 0; dblk < 4; ++dblk) {
      f32x16 o1 = *(const f32x16*)(src + dblk * 16);
#pragma unroll
      for (int r = 0; r < 16; ++r) {
        int d = dblk * 32 + (r & 3) + 8 * (r >> 2) + 4 * hi32;
        int srow = h * 512 + d * 4 + qhi;
        size_t o = ((size_t)b * 2048 + srow) * 512 + col;
        out[o] = (oacc[dblk][r] + o1[r]) * inv + queries[o];
      }
    }
  }
}

extern "C" void kernel_launch(void* const* d_in, const int* in_sizes, int n_in,
                              void* d_out, int out_size, void* d_ws, size_t ws_size,
                              hipStream_t stream) {
  const float* queries = (const float*)d_in[0];
  const float* keys    = (const float*)d_in[1];
  const float* values  = (const float*)d_in[2];
  const int*   mask    = (const int*)d_in[3];
  const float* Wq = (const float*)d_in[4];
  const float* bq = (const float*)d_in[5];
  const float* Wk = (const float*)d_in[6];
  const float* bk = (const float*)d_in[7];
  const float* Wv = (const float*)d_in[8];
  const float* bv = (const float*)d_in[9];
  float* out = (float*)d_out;

  const size_t perX = (size_t)8192 * 512;
  __bf16* qhp = (__bf16*)d_ws;
  __bf16* khp = qhp + perX;
  __bf16* vtp = khp + perX;

  gemm_kernel<<<dim3(64, 4, 3), dim3(256), 0, stream>>>(
      queries, keys, values, Wq, Wk, Wv, bq, bk, bv, mask, qhp, khp, vtp);

  attn_kernel<<<dim3(512), dim3(256), 0, stream>>>(qhp, khp, vtp, queries, out);
}

// Round 8
// 110.831 us; speedup vs baseline: 1.0015x; 1.0015x over previous
//
#include <hip/hip_runtime.h>
#include <hip/hip_bf16.h>

typedef __attribute__((ext_vector_type(8)))  __bf16 bf16x8;
typedef __attribute__((ext_vector_type(4)))  __bf16 bf16x4;
typedef __attribute__((ext_vector_type(2)))  __bf16 bf16x2;
typedef __attribute__((ext_vector_type(4)))  float  f32x4;
typedef __attribute__((ext_vector_type(16))) float  f32x16;

#define MFMA16(a,b,c) __builtin_amdgcn_mfma_f32_16x16x32_bf16((a),(b),(c),0,0,0)
#define MFMA32(a,b,c) __builtin_amdgcn_mfma_f32_32x32x16_bf16((a),(b),(c),0,0,0)

__device__ inline void gload_lds16(const __bf16* g, __bf16* l) {
  __builtin_amdgcn_global_load_lds(
      (const __attribute__((address_space(1))) void*)g,
      (__attribute__((address_space(3))) void*)l, 16, 0, 0);
}

// ---------------------------------------------------------------------------
// Projection GEMM, f32 inputs with FUSED bf16 conversion in reg-staging.
// dst = relu(X @ W^T + bias) * oscale. One barrier per k-step:
//   issue f32 loads(t+1) -> sync -> MFMA(cur) -> cvt+ds_write(cur^1).
// z=0: Q scaled by log2e/sqrt(128), masked rows zeroed -> [bh][s][d].
// z=1: K [bh][s][d]. z=2: V^T [bh][d][s].
// ---------------------------------------------------------------------------
__global__ __launch_bounds__(256, 2) void gemm_kernel(
    const float* __restrict__ Xq, const float* __restrict__ Xk,
    const float* __restrict__ Xv, const float* __restrict__ Wq,
    const float* __restrict__ Wk, const float* __restrict__ Wv,
    const float* __restrict__ bq, const float* __restrict__ bk,
    const float* __restrict__ bv, const int* __restrict__ mask,
    __bf16* __restrict__ dq, __bf16* __restrict__ dk, __bf16* __restrict__ dv)
{
  const int which = blockIdx.z;
  const float* X    = which == 0 ? Xq : which == 1 ? Xk : Xv;
  const float* W    = which == 0 ? Wq : which == 1 ? Wk : Wv;
  const float* bias = which == 0 ? bq : which == 1 ? bk : bv;
  __bf16* dst       = which == 0 ? dq : which == 1 ? dk : dv;
  const float oscale = which == 0 ? 0.12751744710339033f : 1.0f; // log2e/sqrt(128)
  const int mode = (which == 2);

  // [128][64] bf16, 16B slot s stored at s^(row&7)
  __shared__ __align__(16) __bf16 Al[2][128 * 64];
  __shared__ __align__(16) __bf16 Bl[2][128 * 64];

  const int tid  = threadIdx.x;
  const int lane = tid & 63;
  const int w    = tid >> 6;
  const int wr = w >> 1, wc = w & 1;
  const int mbase = blockIdx.x * 128;
  const int nbase = blockIdx.y * 128;
  const int arow = lane & 15;
  const int hi   = lane >> 4;

  f32x4 acc[4][4] = {};
  float4 ar[8], br[8];

  auto issue = [&](int k0) {
#pragma unroll
    for (int i = 0; i < 8; ++i) {
      int idx = tid + i * 256;
      int r = idx >> 4, c = (idx & 15) * 4;
      ar[i] = *(const float4*)&X[(size_t)(mbase + r) * 512 + k0 + c];
      br[i] = *(const float4*)&W[(size_t)(nbase + r) * 512 + k0 + c];
    }
  };
  auto commit = [&](int buf) {
#pragma unroll
    for (int i = 0; i < 8; ++i) {
      int idx = tid + i * 256;
      int r = idx >> 4, c4 = idx & 15;
      int slot = c4 >> 1, half = c4 & 1;
      int addr = r * 64 + (slot ^ (r & 7)) * 8 + half * 4;
      bf16x4 av, bv2;
      av[0] = (__bf16)ar[i].x; av[1] = (__bf16)ar[i].y;
      av[2] = (__bf16)ar[i].z; av[3] = (__bf16)ar[i].w;
      bv2[0] = (__bf16)br[i].x; bv2[1] = (__bf16)br[i].y;
      bv2[2] = (__bf16)br[i].z; bv2[3] = (__bf16)br[i].w;
      *(bf16x4*)&Al[buf][addr] = av;
      *(bf16x4*)&Bl[buf][addr] = bv2;
    }
  };

  issue(0);
  commit(0);

  for (int t = 0; t < 8; ++t) {
    const int cur = t & 1;
    if (t < 7) issue((t + 1) * 64);
    __syncthreads();

    __builtin_amdgcn_s_setprio(1);
#pragma unroll
    for (int kk = 0; kk < 2; ++kk) {
      bf16x8 af[4], bfr[4];
#pragma unroll
      for (int m = 0; m < 4; ++m) {
        int row = wr * 64 + m * 16 + arow;
        int sl  = ((kk * 4 + hi) ^ (row & 7)) * 8;
        af[m] = *(bf16x8*)&Al[cur][row * 64 + sl];
      }
#pragma unroll
      for (int n = 0; n < 4; ++n) {
        int row = wc * 64 + n * 16 + arow;
        int sl  = ((kk * 4 + hi) ^ (row & 7)) * 8;
        bfr[n] = *(bf16x8*)&Bl[cur][row * 64 + sl];
      }
#pragma unroll
      for (int m = 0; m < 4; ++m)
#pragma unroll
        for (int n = 0; n < 4; ++n)
          acc[m][n] = MFMA16(af[m], bfr[n], acc[m][n]);
    }
    __builtin_amdgcn_s_setprio(0);

    if (t < 7) commit(cur ^ 1);
  }

  // Epilogue: bias + relu + oscale (+ Q row-mask zeroing), bf16 store.
#pragma unroll
  for (int n = 0; n < 4; ++n) {
    int col = nbase + wc * 64 + n * 16 + arow;
    float bsv = bias[col];
    int h = col >> 7, d = col & 127;
#pragma unroll
    for (int m = 0; m < 4; ++m) {
      int row0 = mbase + wr * 64 + m * 16 + hi * 4;
#pragma unroll
      for (int r = 0; r < 4; ++r) {
        float v = acc[m][n][r] + bsv;
        v = (v > 0.0f ? v : 0.0f) * oscale;
        int mm = row0 + r;
        int b = mm >> 11, s = mm & 2047;
        if (which == 0 && mask[b * 2048 + s] != 0) v = 0.0f;
        if (mode == 0)
          dst[((size_t)(b * 4 + h) * 2048 + s) * 128 + d] = (__bf16)v;
        else
          dst[((size_t)(b * 4 + h) * 128 + d) * 2048 + s] = (__bf16)v;
      }
    }
  }
}

// ---------------------------------------------------------------------------
// Flash attention, fixed-reference softmax. K LDS-staged (swizzled, dbuf,
// counted vmcnt); V direct global->reg. CRITICAL ORDER (vmcnt is FIFO):
// V(t) issued FIRST, then stageK(t+1), then vmcnt(4) -> V(t)+K(t) resident,
// K(t+1) prefetch stays in flight; PV's vf use needs no further drain.
// ---------------------------------------------------------------------------
__global__ __launch_bounds__(256, 2) void attn_kernel(
    const __bf16* __restrict__ qh, const __bf16* __restrict__ kh,
    const __bf16* __restrict__ vt, const float* __restrict__ queries,
    float* __restrict__ out)
{
  __shared__ __align__(16) __bf16 Kl[2][64 * 128];  // [kv][d], slot ^ (row&7)
  __shared__ float Mbuf[64 + 128 * 68];             // merge: Ll + Ob

  const int tid  = threadIdx.x;
  const int lane = tid & 63;
  const int w    = tid >> 6;
  const int qw   = w & 1;
  const int kw   = w >> 1;
  const int r5   = lane & 31;
  const int hi32 = lane >> 5;

  const int blk = blockIdx.x;
  const int xcd = blk & 7;
  const int idx = blk >> 3;
  const int bh  = xcd * 2 + (idx & 1);
  const int qt  = idx >> 1;
  const int b = bh >> 2, h = bh & 3;
  const int qbase = qt * 64 + qw * 32;

  const __bf16* qptr = qh + (size_t)bh * 2048 * 128;
  const __bf16* kptr = kh + (size_t)bh * 2048 * 128;
  const __bf16* vptr = vt + (size_t)bh * 128 * 2048;

  bf16x8 qf[8];
#pragma unroll
  for (int ds = 0; ds < 8; ++ds)
    qf[ds] = *(const bf16x8*)&qptr[(size_t)(qbase + r5) * 128 + ds * 16 + hi32 * 8];

  float l_st = 0.f;
  f32x16 oacc[4] = {};

  auto stageK = [&](int buf, int kv0) {
#pragma unroll
    for (int i = 0; i < 4; ++i) {
      int ob = i * 4096 + w * 1024;
      int o  = ob + lane * 16;
      int r  = o >> 8;
      int s  = ((o >> 4) & 15) ^ (r & 7);
      gload_lds16(kptr + (size_t)(kv0 + r) * 128 + s * 8, &Kl[buf][ob >> 1]);
    }
  };

  stageK(0, 0);

  for (int t = 0; t < 32; ++t) {
    const int cur = t & 1;

    // V fragments for tile t: issued FIRST so they are OLDER than the K
    // prefetch in the vmcnt FIFO.
    bf16x8 vf[4][2];
#pragma unroll
    for (int dblk = 0; dblk < 4; ++dblk)
#pragma unroll
      for (int s = 0; s < 2; ++s) {
        int row  = dblk * 32 + r5;
        int slot = kw * 4 + s * 2 + hi32;
        vf[dblk][s] =
            *(const bf16x8*)&vptr[(size_t)row * 2048 + t * 64 + slot * 8];
      }
    // Pin issue order: stop LLVM sinking the V loads below global_load_lds.
    asm volatile("" ::: "memory");
    __builtin_amdgcn_sched_barrier(0);

    if (t < 31) {
      stageK(cur ^ 1, (t + 1) * 64);
      asm volatile("s_waitcnt vmcnt(4)" ::: "memory");  // V(t)+K(t) resident
    } else {
      asm volatile("s_waitcnt vmcnt(0)" ::: "memory");
    }
    __builtin_amdgcn_s_barrier();

    // QK^T swapped on this wave's kv-half: S[kv][q=lane&31] (log2 domain).
    f32x16 sacc = {};
    __builtin_amdgcn_s_setprio(1);
#pragma unroll
    for (int ds = 0; ds < 8; ++ds) {
      int row = kw * 32 + r5;
      int sl  = ((ds * 2 + hi32) ^ (row & 7)) * 8;
      bf16x8 kf = *(bf16x8*)&Kl[cur][row * 128 + sl];
      sacc = MFMA32(kf, qf[ds], sacc);
    }
    __builtin_amdgcn_s_setprio(0);

    // Fixed-reference softmax: P = exp2(s). Tree-sum to cut dep chain.
    float ps[16];
#pragma unroll
    for (int r = 0; r < 16; ++r) {
      ps[r] = __builtin_amdgcn_exp2f(sacc[r]);
      sacc[r] = ps[r];
    }
#pragma unroll
    for (int st = 1; st < 16; st <<= 1)
#pragma unroll
      for (int r = 0; r < 16; r += 2 * st)
        ps[r] += ps[r + st];
    l_st += ps[0];

    // P -> B-frags in-register: bf16 pack pairs + permlane32_swap.
    unsigned pk[8];
#pragma unroll
    for (int g = 0; g < 8; ++g) {
      bf16x2 tp;
      tp[0] = (__bf16)sacc[2 * g];
      tp[1] = (__bf16)sacc[2 * g + 1];
      pk[g] = __builtin_bit_cast(unsigned, tp);
    }
    bf16x8 pf[2];
#pragma unroll
    for (int s = 0; s < 2; ++s) {
      unsigned a0 = pk[4 * s + 0], a1 = pk[4 * s + 1];
      unsigned b0 = pk[4 * s + 2], b1 = pk[4 * s + 3];
      asm("v_permlane32_swap_b32 %0, %1" : "+v"(a0), "+v"(b0));
      asm("v_permlane32_swap_b32 %0, %1" : "+v"(a1), "+v"(b1));
      union { unsigned u[4]; bf16x8 v; } pu;
      pu.u[0] = a0; pu.u[1] = a1; pu.u[2] = b0; pu.u[3] = b1;
      pf[s] = pu.v;
    }

    __builtin_amdgcn_s_setprio(1);
#pragma unroll
    for (int dblk = 0; dblk < 4; ++dblk)
#pragma unroll
      for (int s = 0; s < 2; ++s)
        oacc[dblk] = MFMA32(vf[dblk][s], pf[s], oacc[dblk]);
    __builtin_amdgcn_s_setprio(0);

    __builtin_amdgcn_s_barrier();
  }

  // ---- merge kv-halves (l and O are plain sums), then epilogue ----
  float l_tot = l_st + __shfl_xor(l_st, 32);

  __syncthreads();
  float* Ll = Mbuf;                  // [2 qw][32 q]
  float* Ob = Mbuf + 64;             // kw=1 oacc, stride 68 f32/lane

  if (kw == 1) {
    if (hi32 == 0) Ll[qw * 32 + r5] = l_tot;
    float* dst = Ob + (size_t)(qw * 64 + lane) * 68;
#pragma unroll
    for (int dblk = 0; dblk < 4; ++dblk)
      *(f32x16*)(dst + dblk * 16) = oacc[dblk];
  }
  __syncthreads();

  if (kw == 0) {
    float l1 = Ll[qw * 32 + r5];
    float inv = 1.0f / (l_tot + l1);
    const float* src = Ob + (size_t)(qw * 64 + lane) * 68;

    const int qhi = qt >> 3;
    const int col = (qt & 7) * 64 + qw * 32 + r5;
#pragma unroll
    for (int dblk = 0; dblk < 4; ++dblk) {
      f32x16 o1 = *(const f32x16*)(src + dblk * 16);
#pragma unroll
      for (int r = 0; r < 16; ++r) {
        int d = dblk * 32 + (r & 3) + 8 * (r >> 2) + 4 * hi32;
        int srow = h * 512 + d * 4 + qhi;
        size_t o = ((size_t)b * 2048 + srow) * 512 + col;
        out[o] = (oacc[dblk][r] + o1[r]) * inv + queries[o];
      }
    }
  }
}

extern "C" void kernel_launch(void* const* d_in, const int* in_sizes, int n_in,
                              void* d_out, int out_size, void* d_ws, size_t ws_size,
                              hipStream_t stream) {
  const float* queries = (const float*)d_in[0];
  const float* keys    = (const float*)d_in[1];
  const float* values  = (const float*)d_in[2];
  const int*   mask    = (const int*)d_in[3];
  const float* Wq = (const float*)d_in[4];
  const float* bq = (const float*)d_in[5];
  const float* Wk = (const float*)d_in[6];
  const float* bk = (const float*)d_in[7];
  const float* Wv = (const float*)d_in[8];
  const float* bv = (const float*)d_in[9];
  float* out = (float*)d_out;

  const size_t perX = (size_t)8192 * 512;
  __bf16* qhp = (__bf16*)d_ws;
  __bf16* khp = qhp + perX;
  __bf16* vtp = khp + perX;

  gemm_kernel<<<dim3(64, 4, 3), dim3(256), 0, stream>>>(
      queries, keys, values, Wq, Wk, Wv, bq, bk, bv, mask, qhp, khp, vtp);

  attn_kernel<<<dim3(512), dim3(256), 0, stream>>>(qhp, khp, vtp, queries, out);
}

// Round 10
// 80.921 us; speedup vs baseline: 1.3717x; 1.3696x over previous
//
#include <hip/hip_runtime.h>
#include <hip/hip_bf16.h>

typedef __attribute__((ext_vector_type(8)))  __bf16 bf16x8;
typedef __attribute__((ext_vector_type(4)))  __bf16 bf16x4;
typedef __attribute__((ext_vector_type(2)))  __bf16 bf16x2;
typedef __attribute__((ext_vector_type(4)))  float  f32x4;
typedef __attribute__((ext_vector_type(16))) float  f32x16;

#define MFMA16(a,b,c) __builtin_amdgcn_mfma_f32_16x16x32_bf16((a),(b),(c),0,0,0)
#define MFMA32(a,b,c) __builtin_amdgcn_mfma_f32_32x32x16_bf16((a),(b),(c),0,0,0)

__device__ inline void gload_lds16(const __bf16* g, __bf16* l) {
  __builtin_amdgcn_global_load_lds(
      (const __attribute__((address_space(1))) void*)g,
      (__attribute__((address_space(3))) void*)l, 16, 0, 0);
}

// ---------------------------------------------------------------------------
// Projection GEMM, f32 inputs with FUSED bf16 conversion in reg-staging.
// z=0: Q scaled by log2e/sqrt(128), masked rows zeroed -> [bh][s][d].
// z=1: K [bh][s][d].
// z=2: V in MFMA-A-FRAGMENT-LINEAR order per bh: element (d, kv) at
//      idx = unit*512 + hi3*256 + r5*8 + j,
//      unit = ((t*2+kw)*4+dblk)*2+s2, with t=kv>>6, kw=kv[5], s2=kv[4],
//      hi3=kv[3], j=kv&7, dblk=d>>5, r5=d&31. Attn's vf loads are then
//      lane-contiguous 1KB wave transactions (512 elems/unit).
// ---------------------------------------------------------------------------
__global__ __launch_bounds__(256, 2) void gemm_kernel(
    const float* __restrict__ Xq, const float* __restrict__ Xk,
    const float* __restrict__ Xv, const float* __restrict__ Wq,
    const float* __restrict__ Wk, const float* __restrict__ Wv,
    const float* __restrict__ bq, const float* __restrict__ bk,
    const float* __restrict__ bv, const int* __restrict__ mask,
    __bf16* __restrict__ dq, __bf16* __restrict__ dk, __bf16* __restrict__ dv)
{
  const int which = blockIdx.z;
  const float* X    = which == 0 ? Xq : which == 1 ? Xk : Xv;
  const float* W    = which == 0 ? Wq : which == 1 ? Wk : Wv;
  const float* bias = which == 0 ? bq : which == 1 ? bk : bv;
  __bf16* dst       = which == 0 ? dq : which == 1 ? dk : dv;
  const float oscale = which == 0 ? 0.12751744710339033f : 1.0f; // log2e/sqrt(128)

  // [128][64] bf16, 16B slot s stored at s^(row&7)
  __shared__ __align__(16) __bf16 Al[2][128 * 64];
  __shared__ __align__(16) __bf16 Bl[2][128 * 64];

  const int tid  = threadIdx.x;
  const int lane = tid & 63;
  const int w    = tid >> 6;
  const int wr = w >> 1, wc = w & 1;
  const int mbase = blockIdx.x * 128;
  const int nbase = blockIdx.y * 128;
  const int arow = lane & 15;
  const int hi   = lane >> 4;

  f32x4 acc[4][4] = {};
  float4 ar[8], br[8];

  auto issue = [&](int k0) {
#pragma unroll
    for (int i = 0; i < 8; ++i) {
      int idx = tid + i * 256;
      int r = idx >> 4, c = (idx & 15) * 4;
      ar[i] = *(const float4*)&X[(size_t)(mbase + r) * 512 + k0 + c];
      br[i] = *(const float4*)&W[(size_t)(nbase + r) * 512 + k0 + c];
    }
  };
  auto commit = [&](int buf) {
#pragma unroll
    for (int i = 0; i < 8; ++i) {
      int idx = tid + i * 256;
      int r = idx >> 4, c4 = idx & 15;
      int slot = c4 >> 1, half = c4 & 1;
      int addr = r * 64 + (slot ^ (r & 7)) * 8 + half * 4;
      bf16x4 av, bv2;
      av[0] = (__bf16)ar[i].x; av[1] = (__bf16)ar[i].y;
      av[2] = (__bf16)ar[i].z; av[3] = (__bf16)ar[i].w;
      bv2[0] = (__bf16)br[i].x; bv2[1] = (__bf16)br[i].y;
      bv2[2] = (__bf16)br[i].z; bv2[3] = (__bf16)br[i].w;
      *(bf16x4*)&Al[buf][addr] = av;
      *(bf16x4*)&Bl[buf][addr] = bv2;
    }
  };

  issue(0);
  commit(0);

  for (int t = 0; t < 8; ++t) {
    const int cur = t & 1;
    if (t < 7) issue((t + 1) * 64);
    __syncthreads();

    __builtin_amdgcn_s_setprio(1);
#pragma unroll
    for (int kk = 0; kk < 2; ++kk) {
      bf16x8 af[4], bfr[4];
#pragma unroll
      for (int m = 0; m < 4; ++m) {
        int row = wr * 64 + m * 16 + arow;
        int sl  = ((kk * 4 + hi) ^ (row & 7)) * 8;
        af[m] = *(bf16x8*)&Al[cur][row * 64 + sl];
      }
#pragma unroll
      for (int n = 0; n < 4; ++n) {
        int row = wc * 64 + n * 16 + arow;
        int sl  = ((kk * 4 + hi) ^ (row & 7)) * 8;
        bfr[n] = *(bf16x8*)&Bl[cur][row * 64 + sl];
      }
#pragma unroll
      for (int m = 0; m < 4; ++m)
#pragma unroll
        for (int n = 0; n < 4; ++n)
          acc[m][n] = MFMA16(af[m], bfr[n], acc[m][n]);
    }
    __builtin_amdgcn_s_setprio(0);

    if (t < 7) commit(cur ^ 1);
  }

  // Epilogue: bias + relu + oscale (+ Q row-mask zeroing), bf16 store.
#pragma unroll
  for (int n = 0; n < 4; ++n) {
    int col = nbase + wc * 64 + n * 16 + arow;
    float bsv = bias[col];
    int h = col >> 7, d = col & 127;
#pragma unroll
    for (int m = 0; m < 4; ++m) {
      int row0 = mbase + wr * 64 + m * 16 + hi * 4;
#pragma unroll
      for (int r = 0; r < 4; ++r) {
        float v = acc[m][n][r] + bsv;
        v = (v > 0.0f ? v : 0.0f) * oscale;
        int mm = row0 + r;
        int b = mm >> 11, s = mm & 2047;
        if (which == 0 && mask[b * 2048 + s] != 0) v = 0.0f;
        size_t bhoff = (size_t)(b * 4 + h) * (2048 * 128);
        if (which != 2) {
          dst[bhoff + (size_t)s * 128 + d] = (__bf16)v;
        } else {
          // fragment-linear V: (d, kv=s) -> idx (unit stride = 512 elems)
          int tt = s >> 6, kw_ = (s >> 5) & 1, s2 = (s >> 4) & 1;
          int hi3 = (s >> 3) & 1, j = s & 7;
          int dblk = d >> 5, r5 = d & 31;
          size_t unit = (((size_t)tt * 2 + kw_) * 4 + dblk) * 2 + s2;
          dst[bhoff + unit * 512 + hi3 * 256 + r5 * 8 + j] = (__bf16)v;
        }
      }
    }
  }
}

// ---------------------------------------------------------------------------
// Flash attention, fixed-reference softmax. K LDS-staged (swizzled, dbuf,
// counted vmcnt); V direct global->reg from FRAGMENT-LINEAR layout (fully
// coalesced 1KB wave loads). V(t) issued first (vmcnt FIFO), then stageK(t+1),
// then vmcnt(4): V(t)+K(t) resident, K(t+1) prefetch in flight.
// ---------------------------------------------------------------------------
__global__ __launch_bounds__(256, 2) void attn_kernel(
    const __bf16* __restrict__ qh, const __bf16* __restrict__ kh,
    const __bf16* __restrict__ vt, const float* __restrict__ queries,
    float* __restrict__ out)
{
  __shared__ __align__(16) __bf16 Kl[2][64 * 128];  // [kv][d], slot ^ (row&7)
  __shared__ float Mbuf[64 + 128 * 68];             // merge: Ll + Ob

  const int tid  = threadIdx.x;
  const int lane = tid & 63;
  const int w    = tid >> 6;
  const int qw   = w & 1;
  const int kw   = w >> 1;
  const int r5   = lane & 31;
  const int hi32 = lane >> 5;

  const int blk = blockIdx.x;
  const int xcd = blk & 7;
  const int idx = blk >> 3;
  const int bh  = xcd * 2 + (idx & 1);
  const int qt  = idx >> 1;
  const int b = bh >> 2, h = bh & 3;
  const int qbase = qt * 64 + qw * 32;

  const __bf16* qptr = qh + (size_t)bh * 2048 * 128;
  const __bf16* kptr = kh + (size_t)bh * 2048 * 128;
  const __bf16* vptr = vt + (size_t)bh * 2048 * 128;

  bf16x8 qf[8];
#pragma unroll
  for (int ds = 0; ds < 8; ++ds)
    qf[ds] = *(const bf16x8*)&qptr[(size_t)(qbase + r5) * 128 + ds * 16 + hi32 * 8];

  float l_st = 0.f;
  f32x16 oacc[4] = {};

  auto stageK = [&](int buf, int kv0) {
#pragma unroll
    for (int i = 0; i < 4; ++i) {
      int ob = i * 4096 + w * 1024;
      int o  = ob + lane * 16;
      int r  = o >> 8;
      int s  = ((o >> 4) & 15) ^ (r & 7);
      gload_lds16(kptr + (size_t)(kv0 + r) * 128 + s * 8, &Kl[buf][ob >> 1]);
    }
  };

  stageK(0, 0);

  for (int t = 0; t < 32; ++t) {
    const int cur = t & 1;

    // V fragments for tile t: fragment-linear layout -> each load is 64
    // lanes x 16B contiguous (unit stride 512 elems). Issued FIRST so they
    // are OLDER than the K prefetch in the vmcnt FIFO.
    bf16x8 vf[4][2];
#pragma unroll
    for (int dblk = 0; dblk < 4; ++dblk)
#pragma unroll
      for (int s = 0; s < 2; ++s)
        vf[dblk][s] = *(const bf16x8*)
            &vptr[((((size_t)t * 2 + kw) * 4 + dblk) * 2 + s) * 512 + lane * 8];
    // Pin issue order: stop LLVM sinking the V loads below global_load_lds.
    asm volatile("" ::: "memory");
    __builtin_amdgcn_sched_barrier(0);

    if (t < 31) {
      stageK(cur ^ 1, (t + 1) * 64);
      asm volatile("s_waitcnt vmcnt(4)" ::: "memory");  // V(t)+K(t) resident
    } else {
      asm volatile("s_waitcnt vmcnt(0)" ::: "memory");
    }
    __builtin_amdgcn_s_barrier();

    // QK^T swapped on this wave's kv-half: S[kv][q=lane&31] (log2 domain).
    f32x16 sacc = {};
    __builtin_amdgcn_s_setprio(1);
#pragma unroll
    for (int ds = 0; ds < 8; ++ds) {
      int row = kw * 32 + r5;
      int sl  = ((ds * 2 + hi32) ^ (row & 7)) * 8;
      bf16x8 kf = *(bf16x8*)&Kl[cur][row * 128 + sl];
      sacc = MFMA32(kf, qf[ds], sacc);
    }
    __builtin_amdgcn_s_setprio(0);

    // Fixed-reference softmax: P = exp2(s). Tree-sum to cut dep chain.
    float ps[16];
#pragma unroll
    for (int r = 0; r < 16; ++r) {
      ps[r] = __builtin_amdgcn_exp2f(sacc[r]);
      sacc[r] = ps[r];
    }
#pragma unroll
    for (int st = 1; st < 16; st <<= 1)
#pragma unroll
      for (int r = 0; r < 16; r += 2 * st)
        ps[r] += ps[r + st];
    l_st += ps[0];

    // P -> B-frags in-register: bf16 pack pairs + permlane32_swap.
    unsigned pk[8];
#pragma unroll
    for (int g = 0; g < 8; ++g) {
      bf16x2 tp;
      tp[0] = (__bf16)sacc[2 * g];
      tp[1] = (__bf16)sacc[2 * g + 1];
      pk[g] = __builtin_bit_cast(unsigned, tp);
    }
    bf16x8 pf[2];
#pragma unroll
    for (int s = 0; s < 2; ++s) {
      unsigned a0 = pk[4 * s + 0], a1 = pk[4 * s + 1];
      unsigned b0 = pk[4 * s + 2], b1 = pk[4 * s + 3];
      asm("v_permlane32_swap_b32 %0, %1" : "+v"(a0), "+v"(b0));
      asm("v_permlane32_swap_b32 %0, %1" : "+v"(a1), "+v"(b1));
      union { unsigned u[4]; bf16x8 v; } pu;
      pu.u[0] = a0; pu.u[1] = a1; pu.u[2] = b0; pu.u[3] = b1;
      pf[s] = pu.v;
    }

    __builtin_amdgcn_s_setprio(1);
#pragma unroll
    for (int dblk = 0; dblk < 4; ++dblk)
#pragma unroll
      for (int s = 0; s < 2; ++s)
        oacc[dblk] = MFMA32(vf[dblk][s], pf[s], oacc[dblk]);
    __builtin_amdgcn_s_setprio(0);

    __builtin_amdgcn_s_barrier();
  }

  // ---- merge kv-halves (l and O are plain sums), then epilogue ----
  float l_tot = l_st + __shfl_xor(l_st, 32);

  __syncthreads();
  float* Ll = Mbuf;                  // [2 qw][32 q]
  float* Ob = Mbuf + 64;             // kw=1 oacc, stride 68 f32/lane

  if (kw == 1) {
    if (hi32 == 0) Ll[qw * 32 + r5] = l_tot;
    float* dst = Ob + (size_t)(qw * 64 + lane) * 68;
#pragma unroll
    for (int dblk = 0; dblk < 4; ++dblk)
      *(f32x16*)(dst + dblk * 16) = oacc[dblk];
  }
  __syncthreads();

  if (kw == 0) {
    float l1 = Ll[qw * 32 + r5];
    float inv = 1.0f / (l_tot + l1);
    const float* src = Ob + (size_t)(qw * 64 + lane) * 68;

    const int qhi = qt >> 3;
    const int col = (qt & 7) * 64 + qw * 32 + r5;
#pragma unroll
    for (int dblk = 0; dblk < 4; ++dblk) {
      f32x16 o1 = *(const f32x16*)(src + dblk * 16);
#pragma unroll
      for (int r = 0; r < 16; ++r) {
        int d = dblk * 32 + (r & 3) + 8 * (r >> 2) + 4 * hi32;
        int srow = h * 512 + d * 4 + qhi;
        size_t o = ((size_t)b * 2048 + srow) * 512 + col;
        out[o] = (oacc[dblk][r] + o1[r]) * inv + queries[o];
      }
    }
  }
}

extern "C" void kernel_launch(void* const* d_in, const int* in_sizes, int n_in,
                              void* d_out, int out_size, void* d_ws, size_t ws_size,
                              hipStream_t stream) {
  const float* queries = (const float*)d_in[0];
  const float* keys    = (const float*)d_in[1];
  const float* values  = (const float*)d_in[2];
  const int*   mask    = (const int*)d_in[3];
  const float* Wq = (const float*)d_in[4];
  const float* bq = (const float*)d_in[5];
  const float* Wk = (const float*)d_in[6];
  const float* bk = (const float*)d_in[7];
  const float* Wv = (const float*)d_in[8];
  const float* bv = (const float*)d_in[9];
  float* out = (float*)d_out;

  const size_t perX = (size_t)8192 * 512;
  __bf16* qhp = (__bf16*)d_ws;
  __bf16* khp = qhp + perX;
  __bf16* vtp = khp + perX;

  gemm_kernel<<<dim3(64, 4, 3), dim3(256), 0, stream>>>(
      queries, keys, values, Wq, Wk, Wv, bq, bk, bv, mask, qhp, khp, vtp);

  attn_kernel<<<dim3(512), dim3(256), 0, stream>>>(qhp, khp, vtp, queries, out);
}